// Round 6
// baseline (215.569 us; speedup 1.0000x reference)
//
#include <hip/hip_runtime.h>

#define NQ 2048
#define NT 131072
#define DD 64
#define MM 1024
#define NBUCK 512          // coarse buckets: v >> 8
#define BCAP 4608          // per-bucket capacity (mean 3937 over 508 live buckets; +10 sigma)
#define CHUNK 4096         // edges per bin block

// LESSONS (measured): r2 global-atomic CSR scatter: 176us, 155MB writes (XCD
// coherence + line write-allocate). r3 per-edge LDS ds_add scatter: 690us,
// VALUBusy 8% (LDS atomic pipe serializes). r4 fp16 halved gathered bytes,
// bucket -13%. r5 ~7% VALU cut: null (too small to see). bin_yq ~90-95us,
// never measured (below top-5 cutoff) — this round splits phases to measure.

typedef __attribute__((ext_vector_type(2))) _Float16 h2;

#if defined(__has_builtin)
#if __has_builtin(__builtin_amdgcn_fdot2)
#define HAVE_FDOT2 1
#endif
#endif

__device__ __forceinline__ float fdot2(h2 a, h2 b, float c) {
#ifdef HAVE_FDOT2
    return __builtin_amdgcn_fdot2(a, b, c, false);
#else
    return fmaf((float)a.x, (float)b.x, fmaf((float)a.y, (float)b.y, c));
#endif
}

// Fused bin + YX precompute + outXq copy.
// YX16[u] is a 256-half (512 B) row: halves [0..127] = 16 granules of
// {ya[4s..4s+3], yb[4s..4s+3]}; halves [128..191] = xq16; [192..255] = pad.
// One base address per edge serves all three row-phase loads.
__global__ __launch_bounds__(1024) void bin_yq_kernel(
        const int* __restrict__ u_idx, const int* __restrict__ v_idx,
        int* __restrict__ gcurP, unsigned* __restrict__ gbuf,
        const float* __restrict__ Xq,
        const float* __restrict__ Wa, const float* __restrict__ Wb,
        _Float16* __restrict__ YX16,
        float* __restrict__ outXq, int E) {
    __shared__ unsigned stage[CHUNK];
    __shared__ int hist[NBUCK], off[NBUCK], base[NBUCK], cur[NBUCK];
    int tid = threadIdx.x;
    int nchunks = (E + CHUNK - 1) / CHUNK;

    if (blockIdx.x >= nchunks) {        // ---- yq role ----
        int r = (blockIdx.x - nchunks) * 16 + (tid >> 6);
        int j = tid & 63;
        float sa = 0.f, sb = 0.f;
#pragma unroll
        for (int k = 0; k < DD; ++k) {
            float x = Xq[r * DD + k];   // wave-uniform address -> scalar load
            sa = fmaf(x, Wa[k * DD + j], sa);
            sb = fmaf(x, Wb[k * DD + j], sb);
        }
        int rb = r << 8;
        int gbase = rb + (j >> 2) * 8 + (j & 3);
        YX16[gbase] = (_Float16)sa;
        YX16[gbase + 4] = (_Float16)sb;
        float xj = Xq[r * DD + j];
        YX16[rb + 128 + j] = (_Float16)xj;
        YX16[rb + 192 + j] = (_Float16)0.f;   // keep pad clean
        outXq[r * DD + j] = xj;               // replaces the outXq memcpy dispatch
        return;
    }

    // ---- bin role ----
    int e0 = blockIdx.x * CHUNK;
    int n = min(CHUNK, E - e0);
    if (n <= 0) return;

    for (int i = tid; i < NBUCK; i += 1024) hist[i] = 0;
    __syncthreads();

    unsigned p[4];
    int nv = 0;
    int i0 = tid * 4;
    if (i0 + 3 < n) {
        int4 u4 = *(const int4*)(u_idx + e0 + i0);
        int4 v4 = *(const int4*)(v_idx + e0 + i0);
        p[0] = ((unsigned)v4.x << 11) | (unsigned)u4.x;
        p[1] = ((unsigned)v4.y << 11) | (unsigned)u4.y;
        p[2] = ((unsigned)v4.z << 11) | (unsigned)u4.z;
        p[3] = ((unsigned)v4.w << 11) | (unsigned)u4.w;
        nv = 4;
    } else {
        for (int j = 0; j < 4; ++j) {
            if (i0 + j < n) {
                p[j] = ((unsigned)v_idx[e0 + i0 + j] << 11) | (unsigned)u_idx[e0 + i0 + j];
                ++nv;
            }
        }
    }
    for (int j = 0; j < nv; ++j) atomicAdd(&hist[p[j] >> 19], 1);
    __syncthreads();
    if (tid < 64) {   // wave 0: scan 512 buckets, 8 per lane
        int h[8], sum = 0;
#pragma unroll
        for (int j = 0; j < 8; ++j) { h[j] = hist[8 * tid + j]; sum += h[j]; }
        int incl = sum;
#pragma unroll
        for (int d = 1; d < 64; d <<= 1) {
            int y = __shfl_up(incl, d, 64);
            if (tid >= d) incl += y;
        }
        int excl = incl - sum;
#pragma unroll
        for (int j = 0; j < 8; ++j) { off[8 * tid + j] = excl; excl += h[j]; }
    }
    __syncthreads();
    // gcurP: ONE counter per 64B line (stride 16 ints). 250K device atomics on
    // 512 counters: padding removes 16-way false sharing across 8 XCD L2s.
    for (int i = tid; i < NBUCK; i += 1024) {
        base[i] = hist[i] ? atomicAdd(&gcurP[i << 4], hist[i]) : 0;
        cur[i] = off[i];
    }
    __syncthreads();
    for (int j = 0; j < nv; ++j) {
        int pos = atomicAdd(&cur[p[j] >> 19], 1);
        stage[pos] = p[j];
    }
    __syncthreads();
    for (int i = tid; i < n; i += 1024) {
        unsigned q = stage[i];
        int b = q >> 19;
        int idx = base[b] + (i - off[b]);
        if (idx < BCAP) gbuf[(size_t)b * BCAP + idx] = q;
    }
}

// Sort phase, split out for measurement. Reads its gbuf slice twice (hist,
// scatter), builds row-sorted u-list in LDS, then writes it IN-PLACE into the
// first half of its own gbuf slice (as ushorts) + rstart to rofsg.
__global__ __launch_bounds__(1024, 2) void bucket_sort_kernel(
        const int* __restrict__ gcurP,
        unsigned* __restrict__ gbuf,
        int* __restrict__ rofsg) {
    __shared__ unsigned short su[BCAP];
    __shared__ int hist[256], cur[256], rstart[257];
    int tid = threadIdx.x;
    int b = blockIdx.x;
    int n = min(gcurP[b << 4], BCAP);

    if (tid < 256) hist[tid] = 0;
    __syncthreads();
    for (int i = tid; i < n; i += 1024)
        atomicAdd(&hist[(gbuf[(size_t)b * BCAP + i] >> 11) & 255], 1);
    __syncthreads();
    if (tid < 64) {   // wave 0: scan 256 rows, 4 per lane
        int h0 = hist[4 * tid], h1 = hist[4 * tid + 1];
        int h2_ = hist[4 * tid + 2], h3 = hist[4 * tid + 3];
        int tot = h0 + h1 + h2_ + h3;
        int incl = tot;
#pragma unroll
        for (int d = 1; d < 64; d <<= 1) {
            int y = __shfl_up(incl, d, 64);
            if (tid >= d) incl += y;
        }
        int excl = incl - tot;
        rstart[4 * tid] = excl;             cur[4 * tid] = excl;
        rstart[4 * tid + 1] = excl + h0;    cur[4 * tid + 1] = excl + h0;
        rstart[4 * tid + 2] = excl + h0 + h1;       cur[4 * tid + 2] = excl + h0 + h1;
        rstart[4 * tid + 3] = excl + h0 + h1 + h2_; cur[4 * tid + 3] = excl + h0 + h1 + h2_;
        if (tid == 63) rstart[256] = excl + tot;
    }
    __syncthreads();
    for (int i = tid; i < n; i += 1024) {
        unsigned p = gbuf[(size_t)b * BCAP + i];
        int pos = atomicAdd(&cur[(p >> 11) & 255], 1);
        su[pos] = (unsigned short)(p & 0x7FFu);
    }
    __syncthreads();
    // write sorted list back into own slice (uint-packed, coalesced)
    unsigned* dst = gbuf + (size_t)b * BCAP;
    int nw = (n + 1) >> 1;
    for (int i = tid; i < nw; i += 1024)
        dst[i] = ((const unsigned*)su)[i];
    if (tid <= 256) rofsg[b * 257 + tid] = rstart[tid];
}

// 16-lane all-reduce sum via DPP adds (fused v_add_f32_dpp). All call sites
// have full 16-lane groups active (edge validity `ok` is group-uniform).
template <int CTRL>
__device__ __forceinline__ float dpp_add(float x) {
    int xi = __builtin_bit_cast(int, x);
    int yi = __builtin_amdgcn_update_dpp(xi, xi, CTRL, 0xF, 0xF, true);
    return x + __builtin_bit_cast(float, yi);
}
__device__ __forceinline__ float red16(float x) {
    x = dpp_add<0xB1>(x);    // quad_perm [1,0,3,2] : xor 1
    x = dpp_add<0x4E>(x);    // quad_perm [2,3,0,1] : xor 2
    x = dpp_add<0x124>(x);   // row_ror:4
    x = dpp_add<0x128>(x);   // row_ror:8
    return x;
}

// Pure row phase. One row per wave, 8 edges/iter (2 per 16-lane group),
// wave-uniform deg, tails gated by a=0 selects. Merged YX row: one base
// per edge, y + xq via offsets.
__global__ __launch_bounds__(1024, 2) void row_kernel(
        const float* __restrict__ Xq,
        const float* __restrict__ Xt,
        const _Float16* __restrict__ YX16,
        const float* __restrict__ ba,
        const float* __restrict__ bb,
        const unsigned* __restrict__ gbuf,
        const int* __restrict__ rofsg,
        const int* __restrict__ uc,
        float* __restrict__ outXt) {
    __shared__ unsigned short su[BCAP];
    __shared__ int rstart[257];
    int tid = threadIdx.x;
    int b = blockIdx.x;

    if (tid <= 256) rstart[tid] = rofsg[b * 257 + tid];
    __syncthreads();
    int n = rstart[256];
    int nw = (n + 1) >> 1;
    const unsigned* src = gbuf + (size_t)b * BCAP;
    for (int i = tid; i < nw; i += 1024)
        ((unsigned*)su)[i] = src[i];
    __syncthreads();

    int lane = tid & 63;
    int w = tid >> 6;          // wave 0..15
    int l16 = lane & 15;
    int g = lane >> 4;         // group 0..3
    float ba0 = ba[0], bb0 = bb[0];

    for (int r = w; r < 256; r += 16) {
        int v = (b << 8) + r;
        int startr = rstart[r];
        int deg = rstart[r + 1] - startr;   // wave-uniform
        if (deg == 0) {
            if (g == 0) {
                float4 o;
                if (v >= NT - MM) {            // consensus row: Xq[uc[i]] (exact fp32)
                    int u = uc[v - (NT - MM)];
                    o = ((const float4*)(Xq + (size_t)u * DD))[l16];
                } else {
                    o = ((const float4*)(Xt + (size_t)v * DD))[l16];
                }
                ((float4*)(outXt + (size_t)v * DD))[l16] = o;
            }
            continue;
        }
        float4 xt4 = ((const float4*)(Xt + (size_t)v * DD))[l16];
        h2 xt01, xt23;
        xt01.x = (_Float16)xt4.x; xt01.y = (_Float16)xt4.y;
        xt23.x = (_Float16)xt4.z; xt23.y = (_Float16)xt4.w;
        float4 acc = make_float4(0.f, 0.f, 0.f, 0.f);
        float s = 0.f;     // sum a        (softmax denominator)
        float s2 = 0.f;    // sum a*beta   (hoisted xt coefficient)
        for (int base = 0; base < deg; base += 8) {
            int e0 = base + g;
            int e1 = base + 4 + g;
            bool ok0 = e0 < deg, ok1 = e1 < deg;
            int u0 = (int)su[startr + (ok0 ? e0 : 0)];
            int u1 = (int)su[startr + (ok1 ? e1 : 0)];
            const _Float16* P0 = YX16 + ((size_t)u0 << 8);
            const _Float16* P1 = YX16 + ((size_t)u1 << 8);
            float4 y0 = *(const float4*)(P0 + (l16 << 3));
            float4 y1 = *(const float4*)(P1 + (l16 << 3));
            float2 xv0 = *(const float2*)(P0 + 128 + (l16 << 2));
            float2 xv1 = *(const float2*)(P1 + 128 + (l16 << 2));
            float pa0 = fdot2(__builtin_bit_cast(h2, y0.y), xt23,
                       fdot2(__builtin_bit_cast(h2, y0.x), xt01, 0.f));
            float pb0 = fdot2(__builtin_bit_cast(h2, y0.w), xt23,
                       fdot2(__builtin_bit_cast(h2, y0.z), xt01, 0.f));
            float pa1 = fdot2(__builtin_bit_cast(h2, y1.y), xt23,
                       fdot2(__builtin_bit_cast(h2, y1.x), xt01, 0.f));
            float pb1 = fdot2(__builtin_bit_cast(h2, y1.w), xt23,
                       fdot2(__builtin_bit_cast(h2, y1.z), xt01, 0.f));
            pa0 = red16(pa0); pb0 = red16(pb0);
            pa1 = red16(pa1); pb1 = red16(pb1);
            float la0 = pa0 + ba0, la1 = pa1 + ba0;
            float t0 = __expf(la0), t1 = __expf(la1);
            float al0 = la0 > 0.f ? la0 : (t0 - 1.f);
            float al1 = la1 > 0.f ? la1 : (t1 - 1.f);
            float a0 = ok0 ? __expf(al0) : 0.f;   // gate tail edges to zero weight
            float a1 = ok1 ? __expf(al1) : 0.f;
            float be0 = __builtin_amdgcn_rcpf(1.f + __expf(-(pb0 + bb0)));
            float be1 = __builtin_amdgcn_rcpf(1.f + __expf(-(pb1 + bb0)));
            float c20 = a0 * be0, c21 = a1 * be1;   // a*beta  (xt coeff)
            float c10 = a0 - c20, c11 = a1 - c21;   // a*(1-beta) (xq coeff)
            h2 q0a = __builtin_bit_cast(h2, xv0.x), q0b = __builtin_bit_cast(h2, xv0.y);
            h2 q1a = __builtin_bit_cast(h2, xv1.x), q1b = __builtin_bit_cast(h2, xv1.y);
            acc.x = fmaf((float)q0a.x, c10, acc.x);
            acc.y = fmaf((float)q0a.y, c10, acc.y);
            acc.z = fmaf((float)q0b.x, c10, acc.z);
            acc.w = fmaf((float)q0b.y, c10, acc.w);
            acc.x = fmaf((float)q1a.x, c11, acc.x);
            acc.y = fmaf((float)q1a.y, c11, acc.y);
            acc.z = fmaf((float)q1b.x, c11, acc.z);
            acc.w = fmaf((float)q1b.y, c11, acc.w);
            s += a0 + a1;
            s2 += c20 + c21;
        }
        // combine 4 groups: two xor levels give all lanes the totals.
        acc.x += __shfl_xor(acc.x, 16, 64);
        acc.y += __shfl_xor(acc.y, 16, 64);
        acc.z += __shfl_xor(acc.z, 16, 64);
        acc.w += __shfl_xor(acc.w, 16, 64);
        s     += __shfl_xor(s, 16, 64);
        s2    += __shfl_xor(s2, 16, 64);
        acc.x += __shfl_xor(acc.x, 32, 64);
        acc.y += __shfl_xor(acc.y, 32, 64);
        acc.z += __shfl_xor(acc.z, 32, 64);
        acc.w += __shfl_xor(acc.w, 32, 64);
        s     += __shfl_xor(s, 32, 64);
        s2    += __shfl_xor(s2, 32, 64);
        if (g == 0) {
            float inv = __builtin_amdgcn_rcpf(s);
            float4 o;
            o.x = fmaf(s2, xt4.x, acc.x) * inv;
            o.y = fmaf(s2, xt4.y, acc.y) * inv;
            o.z = fmaf(s2, xt4.z, acc.z) * inv;
            o.w = fmaf(s2, xt4.w, acc.w) * inv;
            ((float4*)(outXt + (size_t)v * DD))[l16] = o;
        }
    }
}

extern "C" void kernel_launch(void* const* d_in, const int* in_sizes, int n_in,
                              void* d_out, int out_size, void* d_ws, size_t ws_size,
                              hipStream_t stream) {
    const float* Xq = (const float*)d_in[0];
    const float* Xt = (const float*)d_in[1];
    const float* Wa = (const float*)d_in[2];
    const float* ba = (const float*)d_in[3];
    const float* Wb = (const float*)d_in[4];
    const float* bb = (const float*)d_in[5];
    const int* u_idx = (const int*)d_in[6];
    const int* v_idx = (const int*)d_in[7];
    const int* uc = (const int*)d_in[8];
    const int* vc = (const int*)d_in[9];
    const int E = in_sizes[6];
    (void)vc;

    float* out = (float*)d_out;
    float* outXq = out;                 // NQ*DD
    float* outXt = out + NQ * DD;       // NT*DD

    char* ws = (char*)d_ws;
    _Float16* YX16 = (_Float16*)ws;   ws += (size_t)NQ * 256 * sizeof(_Float16);       // 1M
    int* gcurP = (int*)ws;            ws += (size_t)NBUCK * 16 * sizeof(int);          // 32K
    int* rofsg = (int*)ws;            ws += (size_t)NBUCK * 257 * sizeof(int);         // 526K
    ws = (char*)(((size_t)ws + 255) & ~(size_t)255);
    unsigned* gbuf = (unsigned*)ws;   ws += (size_t)NBUCK * BCAP * sizeof(unsigned);   // 9.4M

    hipMemsetAsync(gcurP, 0, (size_t)NBUCK * 16 * sizeof(int), stream);

    int nchunks = (E + CHUNK - 1) / CHUNK;
    bin_yq_kernel<<<nchunks + NQ / 16, 1024, 0, stream>>>(
        u_idx, v_idx, gcurP, gbuf, Xq, Wa, Wb, YX16, outXq, E);

    bucket_sort_kernel<<<NBUCK, 1024, 0, stream>>>(gcurP, gbuf, rofsg);

    row_kernel<<<NBUCK, 1024, 0, stream>>>(Xq, Xt, YX16, ba, bb, gbuf, rofsg,
                                           uc, outXt);
}